// Round 1
// baseline (111.366 us; speedup 1.0000x reference)
//
#include <hip/hip_runtime.h>
#include <hip/hip_bf16.h>

// Problem constants (from reference): B=64, N=1024, D=8, S=16
#define BB 64
#define NN 1024
#define DD 8
#define SS 16
#define DS 128           // D*S

typedef __attribute__((ext_vector_type(8))) short short8;
typedef __attribute__((ext_vector_type(4))) float floatx4;

typedef __attribute__((address_space(1))) const unsigned int glds_src;
typedef __attribute__((address_space(3))) unsigned int glds_dst;

static __device__ __forceinline__ unsigned short f2bf(float f) {
    unsigned int u = __float_as_uint(f);
    unsigned int r = (u + 0x7FFFu + ((u >> 16) & 1u)) >> 16;   // RNE
    return (unsigned short)r;
}

// ---------------- Kernel 1: merged prepass (UNCHANGED, verified) ----------------
__global__ void prepass(const float* __restrict__ x, unsigned short* __restrict__ xT,
                        const float* __restrict__ M, unsigned short* __restrict__ Mb) {
    __shared__ float tile[64 * 68];
    const int t = threadIdx.x;

    if (blockIdx.x < 1024) {                 // ---- convert_M part ----
        int i = (blockIdx.x * 256 + t) * 4;
        float4 v = *(const float4*)(M + i);
        unsigned int p0 = (unsigned int)f2bf(v.x) | ((unsigned int)f2bf(v.y) << 16);
        unsigned int p1 = (unsigned int)f2bf(v.z) | ((unsigned int)f2bf(v.w) << 16);
        *(uint2*)(Mb + i) = make_uint2(p0, p1);
        return;
    }

    const int bid = blockIdx.x - 1024;
    const int i0 = (bid & 15) * 64;
    const int c0 = ((bid >> 4) & 1) * 64;
    const int b  = bid >> 5;
    const float* xb = x + (size_t)b * (NN * DS);

#pragma unroll
    for (int jj = 0; jj < 4; ++jj) {
        int il = (t >> 4) + jj * 16;
        int cl = (t & 15) * 4;
        float4 v = *(const float4*)(xb + (size_t)(i0 + il) * DS + c0 + cl);
        *(float4*)(tile + il * 68 + cl) = v;
    }
    __syncthreads();
    int cr  = t >> 2;
    int iq  = (t & 3) * 16;
    int rot = (t & 3) * 2;
    unsigned int p[8];
#pragma unroll
    for (int j = 0; j < 8; ++j) {
        int jp = (j + rot) & 7;
        unsigned short lo = f2bf(tile[(iq + 2 * jp + 0) * 68 + cr]);
        unsigned short hi = f2bf(tile[(iq + 2 * jp + 1) * 68 + cr]);
        p[jp] = (unsigned int)lo | ((unsigned int)hi << 16);
    }
    unsigned short* dst = xT + (size_t)b * (NN * DS) + (size_t)(c0 + cr) * NN + i0 + iq;
    *(uint4*)(dst + 0) = make_uint4(p[0], p[1], p[2], p[3]);
    *(uint4*)(dst + 8) = make_uint4(p[4], p[5], p[6], p[7]);
}

// ---------------- Kernel 2: deep-pipelined fused GEMM ----------------
// BM=256 (o) x BN=128 (ds, one b) x BK=64. 512 threads = 8 waves (2M x 4N),
// per-wave 128x32 output (8 m-frags x 2 n-frags of 16x16x32 bf16 MFMA).
// Triple-buffered LDS (A 3x32KB + B 3x16KB = 144KB -> 1 block/CU, grid=256=CU count).
// Two phases per K-tile (one per k-sub 32); counted s_waitcnt vmcnt(6) per tile
// (T3+T4 from the 8-phase template), setprio around the 16-MFMA cluster (T5),
// XOR-granule swizzle on stage-source and ds_read (T2).
//
// Per-thread glds ledger (6 glds per K-tile: A j0..3, B j0..1):
//   prologue: stage(0), stage(1)  -> outstanding [0:6, 1:6]
//   vmcnt(6) retires tile0; loop t: phase0 issues half of stage(t+2), phase1 the
//   other half then vmcnt(6) retires tile t+1. Tail: t=14 ends with vmcnt(0), t=15 bare.
__global__ __launch_bounds__(512, 2) void gemm_fused(
    const unsigned short* __restrict__ Mb,   // [N][N] bf16, row o, col i (k-contiguous)
    const unsigned short* __restrict__ xT,   // [B][DS][N] bf16, row ds, col i (k-contiguous)
    const float* __restrict__ w_syn,         // [N][D][S]
    const float* __restrict__ b_dend,        // [N][D]
    const float* __restrict__ w_dend,        // [N][D]
    const float* __restrict__ b_soma,        // [N]
    float* __restrict__ out)                 // [B][N]
{
    __shared__ __align__(16) unsigned short As[3 * 256 * 64];  // 96 KB
    __shared__ __align__(16) unsigned short Bs[3 * 128 * 64];  // 48 KB
    __shared__ float ex[256 * 4];                              //  4 KB

    const int t      = threadIdx.x;
    const int b      = blockIdx.x;            // b fastest -> XCD = b%8: xT[b] pinned per XCD
    const int o_base = blockIdx.y * 256;

    const int lane = t & 63;
    const int w    = t >> 6;                  // 0..7
    const int wm   = w >> 2;                  // 0..1 : o half (128 rows)
    const int wn   = w & 3;                   // 0..3 : ds quarter (32 cols)
    const int lm   = lane & 15;
    const int kq   = lane >> 4;               // 0..3

    const char* AgB = (const char*)(Mb + (size_t)o_base * NN);
    const char* BgB = (const char*)(xT + (size_t)b * (NN * DS));

    // staging: one glds = 64 lanes x 16B = 8 rows x 128B. slot (lane&7) holds
    // global granule (lane&7)^(row&7); row = base + (lane>>3).
    const int r8 = lane >> 3, l8 = lane & 7;
    const int sg = (l8 ^ r8) * 16;
    int offA[4], ldsA[4], offB[2], ldsB[2];
#pragma unroll
    for (int j = 0; j < 4; ++j) {
        offA[j] = (w * 32 + j * 8 + r8) * (NN * 2) + sg;
        ldsA[j] = (w * 32 + j * 8) * 128;      // byte offset of row-group base
    }
#pragma unroll
    for (int j = 0; j < 2; ++j) {
        offB[j] = (w * 16 + j * 8 + r8) * (NN * 2) + sg;
        ldsB[j] = (w * 16 + j * 8) * 128;
    }

#define STAGE_H0(TT, BUF) do { const int kb_ = (TT) * 128;                                            \
    __builtin_amdgcn_global_load_lds((glds_src*)(AgB + offA[0] + kb_),                                \
        (glds_dst*)((char*)As + (BUF) * 32768 + ldsA[0]), 16, 0, 0);                                  \
    __builtin_amdgcn_global_load_lds((glds_src*)(AgB + offA[1] + kb_),                                \
        (glds_dst*)((char*)As + (BUF) * 32768 + ldsA[1]), 16, 0, 0);                                  \
    __builtin_amdgcn_global_load_lds((glds_src*)(BgB + offB[0] + kb_),                                \
        (glds_dst*)((char*)Bs + (BUF) * 16384 + ldsB[0]), 16, 0, 0);                                  \
} while (0)

#define STAGE_H1(TT, BUF) do { const int kb_ = (TT) * 128;                                            \
    __builtin_amdgcn_global_load_lds((glds_src*)(AgB + offA[2] + kb_),                                \
        (glds_dst*)((char*)As + (BUF) * 32768 + ldsA[2]), 16, 0, 0);                                  \
    __builtin_amdgcn_global_load_lds((glds_src*)(AgB + offA[3] + kb_),                                \
        (glds_dst*)((char*)As + (BUF) * 32768 + ldsA[3]), 16, 0, 0);                                  \
    __builtin_amdgcn_global_load_lds((glds_src*)(BgB + offB[1] + kb_),                                \
        (glds_dst*)((char*)Bs + (BUF) * 16384 + ldsB[1]), 16, 0, 0);                                  \
} while (0)

#define NOSTAGE do {} while (0)
#define VM6  asm volatile("s_waitcnt vmcnt(6)" ::: "memory")
#define VM0  asm volatile("s_waitcnt vmcnt(0)" ::: "memory")
#define NOVM do {} while (0)

    // Phase: ds-read this wave's frags (k-sub KS) || issue stage half || tile-boundary
    // vmcnt || barrier; lgkmcnt(0); setprio(1); 16 MFMA; setprio(0); barrier.
#define PHASE(KS, BUFC, STMT_STAGE, STMT_VM) do {                                                     \
    const unsigned short* Ab_ = As + (BUFC) * 16384;                                                  \
    const unsigned short* Bb_ = Bs + (BUFC) * 8192;                                                   \
    short8 af_[8], bf_[2];                                                                            \
    const int gg_ = (((KS) * 4 + kq) ^ (lm & 7)) * 8;                                                 \
    _Pragma("unroll")                                                                                 \
    for (int m_ = 0; m_ < 8; ++m_)                                                                    \
        af_[m_] = *(const short8*)(Ab_ + (wm * 128 + m_ * 16 + lm) * 64 + gg_);                       \
    _Pragma("unroll")                                                                                 \
    for (int n_ = 0; n_ < 2; ++n_)                                                                    \
        bf_[n_] = *(const short8*)(Bb_ + (wn * 32 + n_ * 16 + lm) * 64 + gg_);                        \
    STMT_STAGE;                                                                                       \
    STMT_VM;                                                                                          \
    __builtin_amdgcn_s_barrier();                                                                     \
    asm volatile("s_waitcnt lgkmcnt(0)" ::: "memory");                                                \
    __builtin_amdgcn_sched_barrier(0);                                                                \
    __builtin_amdgcn_s_setprio(1);                                                                    \
    _Pragma("unroll")                                                                                 \
    for (int m_ = 0; m_ < 8; ++m_)                                                                    \
        _Pragma("unroll")                                                                             \
        for (int n_ = 0; n_ < 2; ++n_)                                                                \
            acc[m_][n_] = __builtin_amdgcn_mfma_f32_16x16x32_bf16(af_[m_], bf_[n_], acc[m_][n_], 0, 0, 0); \
    __builtin_amdgcn_s_setprio(0);                                                                    \
    __builtin_amdgcn_s_barrier();                                                                     \
} while (0)

    floatx4 acc[8][2] = {};

    // prologue: tiles 0 and 1 fully staged; wait tile0 (leave tile1's 6 in flight)
    STAGE_H0(0, 0); STAGE_H1(0, 0);
    STAGE_H0(1, 1); STAGE_H1(1, 1);
    VM6;
    __builtin_amdgcn_s_barrier();

    for (int kt = 0; kt < 14; ++kt) {
        const int bufc = kt % 3;
        const int bufs = (kt + 2) % 3;
        PHASE(0, bufc, STAGE_H0(kt + 2, bufs), NOVM);
        PHASE(1, bufc, STAGE_H1(kt + 2, bufs), VM6);   // retires tile kt+1
    }
    // kt = 14 (buf 2): tile 15 already staged; drain it at tile boundary
    PHASE(0, 2, NOSTAGE, NOVM);
    PHASE(1, 2, NOSTAGE, VM0);
    // kt = 15 (buf 0): nothing in flight
    PHASE(0, 0, NOSTAGE, NOVM);
    PHASE(1, 0, NOSTAGE, NOVM);

#undef PHASE
#undef STAGE_H0
#undef STAGE_H1

    // ---- register epilogue (same math as verified R3-R7, re-indexed) ----
    // acc[m][n][rg]: o = o_base + wm*128 + m*16 + kq*4 + rg ; ds = wn*32 + n*16 + lm
    // => dendrite d = wn*2 + n, synapse s = lm. Butterfly over lm (16-lane quad).
    float keep[2][2];
#pragma unroll
    for (int m = 0; m < 8; ++m) {
#pragma unroll
        for (int rg = 0; rg < 4; ++rg) {
            const int o = o_base + wm * 128 + m * 16 + kq * 4 + rg;
#pragma unroll
            for (int n = 0; n < 2; ++n) {
                const int d = wn * 2 + n;
                float p = acc[m][n][rg] * w_syn[o * DS + d * SS + lm];
                p += __shfl_xor(p, 1);
                p += __shfl_xor(p, 2);
                p += __shfl_xor(p, 4);
                p += __shfl_xor(p, 8);         // 16-lane quad holds sum_s
                if (lm == (m & 3) * 4 + rg) keep[m >> 2][n] = p;
            }
        }
    }
    // lane lm finalizes o's (m = lm>>2 and lm>>2 + 4, rg = lm&3): two o per lane
#pragma unroll
    for (int mh = 0; mh < 2; ++mh) {
        const int o_loc = wm * 128 + mh * 64 + (lm >> 2) * 16 + kq * 4 + (lm & 3);
        const int o     = o_base + o_loc;
        float part = 0.f;
#pragma unroll
        for (int n = 0; n < 2; ++n) {
            const int d = wn * 2 + n;
            float pre = keep[mh][n] + b_dend[o * DD + d];
            part += tanhf(pre) * w_dend[o * DD + d];
        }
        ex[o_loc * 4 + wn] = part;             // 4 wn-waves cover d=0..7
    }
    __syncthreads();
    if (t < 256) {
        float soma = ex[t * 4] + ex[t * 4 + 1] + ex[t * 4 + 2] + ex[t * 4 + 3]
                   + b_soma[o_base + t];
        out[(size_t)b * NN + o_base + t] = 1.f / (1.f + __expf(-soma));
    }
}

extern "C" void kernel_launch(void* const* d_in, const int* in_sizes, int n_in,
                              void* d_out, int out_size, void* d_ws, size_t ws_size,
                              hipStream_t stream) {
    const float* x      = (const float*)d_in[0];   // [B,N,D,S]
    const float* M      = (const float*)d_in[1];   // [N,N]
    const float* w_syn  = (const float*)d_in[2];   // [N,D,S]
    const float* b_dend = (const float*)d_in[3];   // [N,D]
    const float* w_dend = (const float*)d_in[4];   // [N,D]
    const float* b_soma = (const float*)d_in[5];   // [N]
    float* out = (float*)d_out;

    unsigned short* xT = (unsigned short*)d_ws;                 // [B][DS][N] bf16 : 16 MiB
    unsigned short* Mb = xT + (size_t)BB * NN * DS;             // [N][N]   bf16 :  2 MiB

    prepass   <<<dim3(1024 + 2048), 256, 0, stream>>>(x, xT, M, Mb);
    gemm_fused<<<dim3(BB, NN / 256), 512, 0, stream>>>(Mb, xT, w_syn, b_dend, w_dend, b_soma, out);
}